// Round 9
// baseline (68.683 us; speedup 1.0000x reference)
//
#include <hip/hip_runtime.h>
#include <hip/hip_bf16.h>
#include <math.h>

// CARAFE on MI355X (gfx950), r9 = r8 kernels, DIAGNOSTIC launch pattern:
// prep x3, enc x3, apply x1 (all idempotent). Delta vs r8 = 2*(prep+enc).
// features: (2,256,64,64) f32 ; w_comp: (64,256) ; b_comp: (64,) ; w_enc: (100,64,3,3)
// out: (2,256,128,128) f32
#define CIN 256

typedef __attribute__((ext_vector_type(8))) short short8v;  // 8 bf16 (4 VGPRs)
typedef __attribute__((ext_vector_type(4))) float f32x4;    // MFMA accum

// ws layout (float units):
//  Bsw   [18ks][8nf][64lane][8] bf16   @ 0       (36864 fl)
//  compB [8192 pix][64 cc] bf16        @ 36864   (262144 fl)
//  wgt   [2][64h][4sub][25tap][64w]    @ 299008  (819200 fl)

__device__ inline ushort f2bf(float x) {
    __hip_bfloat16 b = __float2bfloat16(x);
    return *reinterpret_cast<ushort*>(&b);
}

// lane i <- lane i+1 (lane 63 gets 0): wave_shl:1, bound_ctrl zero-fill
__device__ inline float dpp_shl1(float x) {
    int r = __builtin_amdgcn_update_dpp(0, __builtin_bit_cast(int, x), 0x130, 0xf, 0xf, true);
    return __builtin_bit_cast(float, r);
}
// lane i <- lane i-1 (lane 0 gets 0): wave_shr:1
__device__ inline float dpp_shr1(float x) {
    int r = __builtin_amdgcn_update_dpp(0, __builtin_bit_cast(int, x), 0x138, 0xf, 0xf, true);
    return __builtin_bit_cast(float, r);
}

// Kernel 1: compress GEMM (blocks 0..255, 32 px each) + enc B-fragment prep (256..543).
__global__ __launch_bounds__(256) void prep_compress(const float* __restrict__ w_comp,
                                                     const float* __restrict__ w_enc,
                                                     const float* __restrict__ b_comp,
                                                     const float* __restrict__ feat,
                                                     ushort* __restrict__ Bsw,
                                                     ushort* __restrict__ compB) {
    int bid = blockIdx.x, tid = threadIdx.x;
    if (bid >= 256) {
        // enc GEMM B-frags: k = convtap*64+cc (K=576, 18 ksteps), col o = tap*4+sub (pad 128)
        int i = (bid - 256) * 256 + tid;         // 73728
        int j = i & 7, lane = (i >> 3) & 63, rest = i >> 9;
        int nf = rest & 7, ks = rest >> 3;       // ks 0..17
        int ct = ks >> 1, dh = ct / 3, dw = ct % 3;
        int cc = (ks & 1) * 32 + (lane >> 4) * 8 + j;
        int o  = nf * 16 + (lane & 15);
        float v = (o < 100) ? w_enc[((o * 64 + cc) * 3 + dh) * 3 + dw] : 0.f;
        Bsw[i] = f2bf(v);
        return;
    }
    // ---- compress GEMM block: 32 pixels ----
    __shared__ ushort at[32][264];               // [px][c] bf16, +8 pad
    int p0 = bid * 32;
    int n = p0 >> 12, hw0 = p0 & 4095;
    const float* fb = feat + (size_t)n * CIN * 4096 + hw0;
    {
        int p4 = tid & 7, cr = tid >> 3;
        #pragma unroll
        for (int k = 0; k < 8; ++k) {
            int c = cr + k * 32;
            float4 v = *reinterpret_cast<const float4*>(fb + (size_t)c * 4096 + p4 * 4);
            at[p4 * 4 + 0][c] = f2bf(v.x);
            at[p4 * 4 + 1][c] = f2bf(v.y);
            at[p4 * 4 + 2][c] = f2bf(v.z);
            at[p4 * 4 + 3][c] = f2bf(v.w);
        }
    }
    __syncthreads();
    int lane = tid & 63, nf = tid >> 6;
    int lr = lane & 15, lk = lane >> 4;
    int cc = nf * 16 + lr;
    f32x4 acc0 = {0, 0, 0, 0}, acc1 = {0, 0, 0, 0};
    const float* wrow = w_comp + (size_t)cc * 256;
    #pragma unroll
    for (int ks = 0; ks < 8; ++ks) {
        float4 b0 = *reinterpret_cast<const float4*>(wrow + ks * 32 + lk * 8);
        float4 b1 = *reinterpret_cast<const float4*>(wrow + ks * 32 + lk * 8 + 4);
        short8v b;
        b[0] = (short)f2bf(b0.x); b[1] = (short)f2bf(b0.y);
        b[2] = (short)f2bf(b0.z); b[3] = (short)f2bf(b0.w);
        b[4] = (short)f2bf(b1.x); b[5] = (short)f2bf(b1.y);
        b[6] = (short)f2bf(b1.z); b[7] = (short)f2bf(b1.w);
        short8v a0 = *reinterpret_cast<const short8v*>(&at[lr][ks * 32 + lk * 8]);
        short8v a1 = *reinterpret_cast<const short8v*>(&at[16 + lr][ks * 32 + lk * 8]);
        acc0 = __builtin_amdgcn_mfma_f32_16x16x32_bf16(a0, b, acc0, 0, 0, 0);
        acc1 = __builtin_amdgcn_mfma_f32_16x16x32_bf16(a1, b, acc1, 0, 0, 0);
    }
    float bv = b_comp[cc];
    #pragma unroll
    for (int i = 0; i < 4; ++i) {
        compB[(size_t)(p0 + lk * 4 + i) * 64 + cc]      = f2bf(acc0[i] + bv);
        compB[(size_t)(p0 + 16 + lk * 4 + i) * 64 + cc] = f2bf(acc1[i] + bv);
    }
}

// Kernel 2: enc conv as MFMA GEMM (M=16/block, N=128 pad, K=576) + fused 25-tap softmax.
__global__ __launch_bounds__(512) void enc_gemm_softmax(const ushort* __restrict__ compB,
                                                        const ushort* __restrict__ Bsw,
                                                        float* __restrict__ wgt) {
    int p0 = blockIdx.x * 16;
    int n = p0 >> 12, h = (p0 >> 6) & 63, w0 = p0 & 63;
    int tid = threadIdx.x, lane = tid & 63, nf = tid >> 6;
    int lr = lane & 15, lk = lane >> 4;
    int wpix = w0 + lr;
    f32x4 acc = {0, 0, 0, 0};
    #pragma unroll
    for (int ks = 0; ks < 18; ++ks) {
        int ct = ks >> 1, dh = ct / 3, dw = ct - dh * 3;
        int hh = h + dh - 1;
        if ((unsigned)hh >= 64u) continue;     // block-uniform
        int ww = wpix + dw - 1;
        short8v a = {};
        if ((unsigned)ww < 64u)
            a = *reinterpret_cast<const short8v*>(
                    compB + ((size_t)(n * 4096 + hh * 64 + ww) * 64 + (ks & 1) * 32 + lk * 8));
        short8v b = *reinterpret_cast<const short8v*>(
                    Bsw + ((size_t)(ks * 8 + nf) * 64 + lane) * 8);
        acc = __builtin_amdgcn_mfma_f32_16x16x32_bf16(a, b, acc, 0, 0, 0);
    }
    __shared__ float kp_lds[16][132];
    __shared__ float kp2[100][17];
    #pragma unroll
    for (int i = 0; i < 4; ++i)
        kp_lds[lk * 4 + i][nf * 16 + lr] = acc[i];
    __syncthreads();
    if (tid < 64) {
        int pl = tid & 15, sub = tid >> 4;
        float v[25], mx = -1e30f;
        #pragma unroll
        for (int t = 0; t < 25; ++t) { v[t] = kp_lds[pl][t * 4 + sub]; mx = fmaxf(mx, v[t]); }
        float s = 0.f;
        #pragma unroll
        for (int t = 0; t < 25; ++t) { v[t] = __expf(v[t] - mx); s += v[t]; }
        float inv = 1.f / s;
        #pragma unroll
        for (int t = 0; t < 25; ++t) kp2[sub * 25 + t][pl] = v[t] * inv;
    }
    __syncthreads();
    // cooperative coalesced store: 100 rows x 16 px, all 512 threads
    {
        int pl = tid & 15, r0 = tid >> 4;        // r0 0..31
        float* wb = wgt + (size_t)((n * 64 + h)) * 6400 + w0 + pl;
        #pragma unroll
        for (int it = 0; it < 4; ++it) {
            int r = it * 32 + r0;                // row = sub*25 + tap
            if (r < 100) wb[r * 64] = kp2[r][pl];
        }
    }
}

// Kernel 3: apply (r6 v3, verbatim): DPP lane shifts, [s][t][w] LDS weights, b32 reads.
__global__ __launch_bounds__(256, 4) void apply_v3(const float* __restrict__ feat,
                                                   const float* __restrict__ wgt,
                                                   float* __restrict__ out) {
    int bid = blockIdx.x;
    int wgid = (bid & 7) * 128 + (bid >> 3);   // XCD swizzle: h fastest within chunk
    int cg = wgid & 7;
    int nh = wgid >> 3;
    int n = nh >> 6, h = nh & 63;
    int tid = threadIdx.x;
    int w  = tid & 63;
    int ci = tid >> 6;
    int c0 = cg * 32 + ci * 8;

    __shared__ float wlds[4 * 25 * 64];        // 25.6 KB: [sub][tap][w]
    {
        const float* wg = wgt + (size_t)nh * 6400;
        #pragma unroll
        for (int it = 0; it < 25; ++it)
            wlds[it * 256 + tid] = wg[it * 256 + tid];
    }
    __syncthreads();

    const float* fbase = feat + ((size_t)(n * CIN + c0)) * 4096;

    float acc[4][8];
    #pragma unroll
    for (int s = 0; s < 4; ++s)
        #pragma unroll
        for (int k = 0; k < 8; ++k) acc[s][k] = 0.f;

    #pragma unroll
    for (int i = 0; i < 5; ++i) {
        int hh = h + i - 2;
        if ((unsigned)hh >= 64u) continue;     // block-uniform; zero-pad rows contribute 0
        float wv[4][5];
        #pragma unroll
        for (int s = 0; s < 4; ++s)
            #pragma unroll
            for (int j = 0; j < 5; ++j)
                wv[s][j] = wlds[(s * 25 + i * 5 + j) * 64 + w];
        #pragma unroll
        for (int k = 0; k < 8; ++k) {
            float v = fbase[(size_t)k * 4096 + (hh << 6) + w];   // one coalesced load
            float vm1 = dpp_shr1(v);
            float vm2 = dpp_shr1(vm1);
            float vp1 = dpp_shl1(v);
            float vp2 = dpp_shl1(vp1);
            float fv[5] = {vm2, vm1, v, vp1, vp2};
            #pragma unroll
            for (int j = 0; j < 5; ++j)
                #pragma unroll
                for (int s = 0; s < 4; ++s)
                    acc[s][k] += fv[j] * wv[s][j];
        }
    }

    #pragma unroll
    for (int k = 0; k < 8; ++k) {
        float* o = out + ((size_t)(n * CIN + c0 + k) * 128 + 2 * h) * 128 + 2 * w;
        *reinterpret_cast<float2*>(o)       = make_float2(acc[0][k], acc[1][k]);
        *reinterpret_cast<float2*>(o + 128) = make_float2(acc[2][k], acc[3][k]);
    }
}

extern "C" void kernel_launch(void* const* d_in, const int* in_sizes, int n_in,
                              void* d_out, int out_size, void* d_ws, size_t ws_size,
                              hipStream_t stream) {
    const float* features = (const float*)d_in[0];
    const float* w_comp   = (const float*)d_in[1];
    const float* b_comp   = (const float*)d_in[2];
    const float* w_enc    = (const float*)d_in[3];
    float* out = (float*)d_out;
    float* ws  = (float*)d_ws;

    ushort* Bsw   = (ushort*)ws;                 // 73728 bf16
    ushort* compB = (ushort*)(ws + 36864);       // 524288 bf16
    float*  wgt   = ws + 299008;                 // 819200 fl

    // DIAGNOSTIC: prep x3, enc x3 (idempotent) to measure per-kernel cost via delta vs r8.
    hipLaunchKernelGGL(prep_compress, dim3(544), dim3(256), 0, stream,
                       w_comp, w_enc, b_comp, features, Bsw, compB);
    hipLaunchKernelGGL(prep_compress, dim3(544), dim3(256), 0, stream,
                       w_comp, w_enc, b_comp, features, Bsw, compB);
    hipLaunchKernelGGL(prep_compress, dim3(544), dim3(256), 0, stream,
                       w_comp, w_enc, b_comp, features, Bsw, compB);
    hipLaunchKernelGGL(enc_gemm_softmax, dim3(512), dim3(512), 0, stream, compB, Bsw, wgt);
    hipLaunchKernelGGL(enc_gemm_softmax, dim3(512), dim3(512), 0, stream, compB, Bsw, wgt);
    hipLaunchKernelGGL(enc_gemm_softmax, dim3(512), dim3(512), 0, stream, compB, Bsw, wgt);
    hipLaunchKernelGGL(apply_v3, dim3(1024), dim3(256), 0, stream, features, wgt, out);
}

// Round 10
// 29.847 us; speedup vs baseline: 2.3011x; 2.3011x over previous
//
#include <hip/hip_runtime.h>
#include <hip/hip_bf16.h>
#include <math.h>

// CARAFE on MI355X (gfx950), r10: enc_v3 (LDS-staged A, swizzled) + wgt [t][w][s4] layout.
// features: (2,256,64,64) f32 ; w_comp: (64,256) ; b_comp: (64,) ; w_enc: (100,64,3,3)
// out: (2,256,128,128) f32
#define CIN 256

typedef __attribute__((ext_vector_type(8))) short short8v;  // 8 bf16 (4 VGPRs)
typedef __attribute__((ext_vector_type(4))) float f32x4;    // MFMA accum

// ws layout (float units):
//  Bsw   [18ks][8nf][64lane][8] bf16    @ 0       (36864 fl)
//  compB [8192 pix][64 cc] bf16         @ 36864   (262144 fl)
//  wgt   [2*64 nh][25 tap][64 w][4 sub] @ 299008  (819200 fl)   <-- NEW layout

__device__ inline ushort f2bf(float x) {
    __hip_bfloat16 b = __float2bfloat16(x);
    return *reinterpret_cast<ushort*>(&b);
}

// lane i <- lane i+1 (lane 63 gets 0): wave_shl:1, bound_ctrl zero-fill
__device__ inline float dpp_shl1(float x) {
    int r = __builtin_amdgcn_update_dpp(0, __builtin_bit_cast(int, x), 0x130, 0xf, 0xf, true);
    return __builtin_bit_cast(float, r);
}
// lane i <- lane i-1 (lane 0 gets 0): wave_shr:1
__device__ inline float dpp_shr1(float x) {
    int r = __builtin_amdgcn_update_dpp(0, __builtin_bit_cast(int, x), 0x138, 0xf, 0xf, true);
    return __builtin_bit_cast(float, r);
}

// Kernel 1: compress GEMM (blocks 0..255, 32 px each) + enc B-fragment prep (256..543).
__global__ __launch_bounds__(256) void prep_compress(const float* __restrict__ w_comp,
                                                     const float* __restrict__ w_enc,
                                                     const float* __restrict__ b_comp,
                                                     const float* __restrict__ feat,
                                                     ushort* __restrict__ Bsw,
                                                     ushort* __restrict__ compB) {
    int bid = blockIdx.x, tid = threadIdx.x;
    if (bid >= 256) {
        // enc GEMM B-frags: k = convtap*64+cc (K=576, 18 ksteps), col o = tap*4+sub (pad 128)
        int i = (bid - 256) * 256 + tid;         // 73728
        int j = i & 7, lane = (i >> 3) & 63, rest = i >> 9;
        int nf = rest & 7, ks = rest >> 3;       // ks 0..17
        int ct = ks >> 1, dh = ct / 3, dw = ct % 3;
        int cc = (ks & 1) * 32 + (lane >> 4) * 8 + j;
        int o  = nf * 16 + (lane & 15);
        float v = (o < 100) ? w_enc[((o * 64 + cc) * 3 + dh) * 3 + dw] : 0.f;
        Bsw[i] = f2bf(v);
        return;
    }
    // ---- compress GEMM block: 32 pixels ----
    __shared__ ushort at[32][264];               // [px][c] bf16, +8 pad
    int p0 = bid * 32;
    int n = p0 >> 12, hw0 = p0 & 4095;
    const float* fb = feat + (size_t)n * CIN * 4096 + hw0;
    {
        int p4 = tid & 7, cr = tid >> 3;
        #pragma unroll
        for (int k = 0; k < 8; ++k) {
            int c = cr + k * 32;
            float4 v = *reinterpret_cast<const float4*>(fb + (size_t)c * 4096 + p4 * 4);
            at[p4 * 4 + 0][c] = f2bf(v.x);
            at[p4 * 4 + 1][c] = f2bf(v.y);
            at[p4 * 4 + 2][c] = f2bf(v.z);
            at[p4 * 4 + 3][c] = f2bf(v.w);
        }
    }
    __syncthreads();
    int lane = tid & 63, nf = tid >> 6;
    int lr = lane & 15, lk = lane >> 4;
    int cc = nf * 16 + lr;
    f32x4 acc0 = {0, 0, 0, 0}, acc1 = {0, 0, 0, 0};
    const float* wrow = w_comp + (size_t)cc * 256;
    #pragma unroll
    for (int ks = 0; ks < 8; ++ks) {
        float4 b0 = *reinterpret_cast<const float4*>(wrow + ks * 32 + lk * 8);
        float4 b1 = *reinterpret_cast<const float4*>(wrow + ks * 32 + lk * 8 + 4);
        short8v b;
        b[0] = (short)f2bf(b0.x); b[1] = (short)f2bf(b0.y);
        b[2] = (short)f2bf(b0.z); b[3] = (short)f2bf(b0.w);
        b[4] = (short)f2bf(b1.x); b[5] = (short)f2bf(b1.y);
        b[6] = (short)f2bf(b1.z); b[7] = (short)f2bf(b1.w);
        short8v a0 = *reinterpret_cast<const short8v*>(&at[lr][ks * 32 + lk * 8]);
        short8v a1 = *reinterpret_cast<const short8v*>(&at[16 + lr][ks * 32 + lk * 8]);
        acc0 = __builtin_amdgcn_mfma_f32_16x16x32_bf16(a0, b, acc0, 0, 0, 0);
        acc1 = __builtin_amdgcn_mfma_f32_16x16x32_bf16(a1, b, acc1, 0, 0, 0);
    }
    float bv = b_comp[cc];
    #pragma unroll
    for (int i = 0; i < 4; ++i) {
        compB[(size_t)(p0 + lk * 4 + i) * 64 + cc]      = f2bf(acc0[i] + bv);
        compB[(size_t)(p0 + 16 + lk * 4 + i) * 64 + cc] = f2bf(acc1[i] + bv);
    }
}

// Kernel 2 (v3): enc GEMM with LDS-staged A-halo (coalesced stage, XOR-swizzled b128
// reads), no bounds checks in k-loop (OOB staged as zeros). Softmax epilogue; wgt
// stored as [nh][tap][w][sub4].
__global__ __launch_bounds__(512, 4) void enc_gemm_softmax(const ushort* __restrict__ compB,
                                                           const ushort* __restrict__ Bsw,
                                                           float* __restrict__ wgt) {
    int p0 = blockIdx.x * 16;
    int n = p0 >> 12, h = (p0 >> 6) & 63, w0 = p0 & 63;
    int tid = threadIdx.x, lane = tid & 63, nf = tid >> 6;
    int lr = lane & 15, lk = lane >> 4;

    __shared__ ushort ctile[3 * 18 * 64];        // 6.75 KB, 16B-unit swizzled: u = q^(p&7)
    if (tid < 432) {                             // 3 rows x 18 px x 8 units
        int q = tid & 7, pp = (tid >> 3) % 18, r = (tid >> 3) / 18;
        int hh = h + r - 1, ww = w0 - 1 + pp;
        uint4 val = {0, 0, 0, 0};
        if ((unsigned)hh < 64u && (unsigned)ww < 64u)
            val = *reinterpret_cast<const uint4*>(
                compB + ((size_t)(n * 4096 + hh * 64 + ww) * 64 + q * 8));
        *reinterpret_cast<uint4*>(&ctile[((r * 18 + pp) * 8 + (q ^ (pp & 7))) * 8]) = val;
    }
    __syncthreads();

    f32x4 acc = {0, 0, 0, 0};
    #pragma unroll
    for (int ks = 0; ks < 18; ++ks) {
        int ct = ks >> 1, half = ks & 1;
        int dh = ct / 3, dw = ct - dh * 3;
        int pp = lr + dw;                        // px index in tile (0..17)
        int q  = half * 4 + lk;
        short8v a = *reinterpret_cast<const short8v*>(
            &ctile[((dh * 18 + pp) * 8 + (q ^ (pp & 7))) * 8]);
        short8v b = *reinterpret_cast<const short8v*>(
            Bsw + ((size_t)(ks * 8 + nf) * 64 + lane) * 8);
        acc = __builtin_amdgcn_mfma_f32_16x16x32_bf16(a, b, acc, 0, 0, 0);
    }

    __shared__ float kp_lds[16][132];
    __shared__ float kp2[100][17];
    #pragma unroll
    for (int i = 0; i < 4; ++i)
        kp_lds[lk * 4 + i][nf * 16 + lr] = acc[i];
    __syncthreads();
    if (tid < 64) {
        int pl = tid & 15, sub = tid >> 4;
        float v[25], mx = -1e30f;
        #pragma unroll
        for (int t = 0; t < 25; ++t) { v[t] = kp_lds[pl][t * 4 + sub]; mx = fmaxf(mx, v[t]); }
        float s = 0.f;
        #pragma unroll
        for (int t = 0; t < 25; ++t) { v[t] = __expf(v[t] - mx); s += v[t]; }
        float inv = 1.f / s;
        #pragma unroll
        for (int t = 0; t < 25; ++t) kp2[sub * 25 + t][pl] = v[t] * inv;
    }
    __syncthreads();
    // cooperative store, layout [nh][t][w][s]: 1600 floats per block
    {
        float* wb = wgt + (size_t)(n * 64 + h) * 6400;
        for (int u = tid; u < 1600; u += 512) {
            int s = u & 3, pl = (u >> 2) & 15, t = u >> 6;
            wb[(t * 64 + w0 + pl) * 4 + s] = kp2[s * 25 + t][pl];
        }
    }
}

// Kernel 3 (v5 = v3 + float4 weight reads from [t][w][s4] layout). Bit-identical math.
__global__ __launch_bounds__(256, 4) void apply_v5(const float* __restrict__ feat,
                                                   const float* __restrict__ wgt,
                                                   float* __restrict__ out) {
    int bid = blockIdx.x;
    int wgid = (bid & 7) * 128 + (bid >> 3);   // XCD swizzle: h fastest within chunk
    int cg = wgid & 7;
    int nh = wgid >> 3;
    int n = nh >> 6, h = nh & 63;
    int tid = threadIdx.x;
    int w  = tid & 63;
    int ci = tid >> 6;
    int c0 = cg * 32 + ci * 8;

    __shared__ float wlds[6400];               // 25.6 KB: [tap25][w64][sub4]
    {
        const float4* wg = reinterpret_cast<const float4*>(wgt + (size_t)nh * 6400);
        float4* wl = reinterpret_cast<float4*>(wlds);
        for (int u = tid; u < 1600; u += 256) wl[u] = wg[u];
    }
    __syncthreads();

    const float* fbase = feat + ((size_t)(n * CIN + c0)) * 4096;

    float acc[4][8];
    #pragma unroll
    for (int s = 0; s < 4; ++s)
        #pragma unroll
        for (int k = 0; k < 8; ++k) acc[s][k] = 0.f;

    #pragma unroll
    for (int i = 0; i < 5; ++i) {
        int hh = h + i - 2;
        if ((unsigned)hh >= 64u) continue;     // block-uniform; zero-pad rows contribute 0
        f32x4 wv[5];
        #pragma unroll
        for (int j = 0; j < 5; ++j)
            wv[j] = *reinterpret_cast<const f32x4*>(&wlds[((i * 5 + j) * 64 + w) * 4]);
        #pragma unroll
        for (int k = 0; k < 8; ++k) {
            float v = fbase[(size_t)k * 4096 + (hh << 6) + w];   // one coalesced load
            float vm1 = dpp_shr1(v);
            float vm2 = dpp_shr1(vm1);
            float vp1 = dpp_shl1(v);
            float vp2 = dpp_shl1(vp1);
            float fv[5] = {vm2, vm1, v, vp1, vp2};
            #pragma unroll
            for (int j = 0; j < 5; ++j)
                #pragma unroll
                for (int s = 0; s < 4; ++s)
                    acc[s][k] += fv[j] * wv[j][s];
        }
    }

    #pragma unroll
    for (int k = 0; k < 8; ++k) {
        float* o = out + ((size_t)(n * CIN + c0 + k) * 128 + 2 * h) * 128 + 2 * w;
        *reinterpret_cast<float2*>(o)       = make_float2(acc[0][k], acc[1][k]);
        *reinterpret_cast<float2*>(o + 128) = make_float2(acc[2][k], acc[3][k]);
    }
}

extern "C" void kernel_launch(void* const* d_in, const int* in_sizes, int n_in,
                              void* d_out, int out_size, void* d_ws, size_t ws_size,
                              hipStream_t stream) {
    const float* features = (const float*)d_in[0];
    const float* w_comp   = (const float*)d_in[1];
    const float* b_comp   = (const float*)d_in[2];
    const float* w_enc    = (const float*)d_in[3];
    float* out = (float*)d_out;
    float* ws  = (float*)d_ws;

    ushort* Bsw   = (ushort*)ws;                 // 73728 bf16
    ushort* compB = (ushort*)(ws + 36864);       // 524288 bf16
    float*  wgt   = ws + 299008;                 // 819200 fl, [nh][t][w][s]

    hipLaunchKernelGGL(prep_compress, dim3(544), dim3(256), 0, stream,
                       w_comp, w_enc, b_comp, features, Bsw, compB);
    hipLaunchKernelGGL(enc_gemm_softmax, dim3(512), dim3(512), 0, stream, compB, Bsw, wgt);
    hipLaunchKernelGGL(apply_v5, dim3(1024), dim3(256), 0, stream, features, wgt, out);
}